// Round 8
// baseline (132.107 us; speedup 1.0000x reference)
//
#include <hip/hip_runtime.h>

#define VOCAB 50257

typedef __attribute__((ext_vector_type(4))) float floatx4;
typedef __attribute__((ext_vector_type(16))) float floatx16;
typedef __attribute__((ext_vector_type(4))) int intx4;
typedef __attribute__((ext_vector_type(8))) int int8v;

// identity E8M0 scales (2^0) in every byte -> opsel-proof
#define SC1 0x7F7F7F7F
#define MFMA32(a, b, c) \
  __builtin_amdgcn_mfma_scale_f32_32x32x64_f8f6f4((a), (b), (c), 4, 0, 0, SC1, 0, SC1)

// ---------------------------------------------------------------------------
// fp4 e2m1 quantizer (software RNE-ish to grid {0,.5,1,1.5,2,3,4,6}), x256.
// ---------------------------------------------------------------------------
static __device__ __forceinline__ unsigned fp4q(float v) {
  float a = fabsf(v) * 256.f;
  unsigned s = (v < 0.f) ? 8u : 0u;
  unsigned c;
  if (a < 0.25f) c = 0;
  else if (a < 0.75f) c = 1;
  else if (a < 1.25f) c = 2;
  else if (a < 1.75f) c = 3;
  else if (a < 2.5f)  c = 4;
  else if (a < 3.5f)  c = 5;
  else if (a < 5.0f)  c = 6;
  else c = 7;
  return s | c;
}

// ---------------------------------------------------------------------------
// Weight pre-shuffle for 32x32x64 scaled MFMA, fp32 -> fp4 (x256), frag-major.
// A-frag (by analogy with verified 16x16x128): A[m = lane&31]
//   [k = 32*(lane>>5) + 8*r + j], r = dword 0..3, j = nibble (bits 4j).
// One b128/lane per 32x64 tile.
// W1f dword idx (per domain, 4096 dw): ((p*64+lane)*4 + r), p = 2*mt+kq,
//   mt=0..7 (32-row tile), kq=0..1 (K-half of 128):
//   -> W1[d][32*mt + (l&31)][64*kq + 32*(l>>5) + 8r + j]
// W2f: p = 4*et + kq, et=0..3 (32-row e-tile), kq=0..3 (K-quarter of 256):
//   -> W2[d][32*et + (l&31)][64*kq + 32*(l>>5) + 8r + j]
// Global fetch addressing in domain_chain is IDENTICAL to the proven R0
// pattern (w*4 tiles of 1024B + lane*16).
// ---------------------------------------------------------------------------
__global__ void prep_weights(const float* __restrict__ W1, const float* __restrict__ W2,
                             unsigned* __restrict__ W1f, unsigned* __restrict__ W2f) {
  int g = blockIdx.x * 256 + threadIdx.x;   // 0..131071
  int arr = g >> 16;
  int s = g & 65535;
  int d = s >> 12;
  int gg = s & 4095;         // dword within domain
  int p = gg >> 8;           // 0..15
  int lane = (gg >> 2) & 63;
  int r = gg & 3;
  int lm = lane & 31, hi = lane >> 5;
  const float* src;
  unsigned* dst;
  if (arr == 0) {
    int mt = p >> 1, kq = p & 1;
    src = W1 + (size_t)(d * 256 + 32 * mt + lm) * 128 + 64 * kq + 32 * hi + 8 * r;
    dst = W1f + (size_t)d * 4096 + gg;
  } else {
    int et = p >> 2, kq = p & 3;
    src = W2 + (size_t)(d * 128 + 32 * et + lm) * 256 + 64 * kq + 32 * hi + 8 * r;
    dst = W2f + (size_t)d * 4096 + gg;
  }
  unsigned pk = 0;
#pragma unroll
  for (int j = 0; j < 8; ++j) pk |= fp4q(src[j]) << (4 * j);
  *dst = pk;
}

static __device__ __forceinline__ int pack_fp8(float a, float b, float c, float d) {
  int v = __builtin_amdgcn_cvt_pk_fp8_f32(a, b, 0, false);
  return __builtin_amdgcn_cvt_pk_fp8_f32(c, d, v, true);
}

// ---------------------------------------------------------------------------
// 32x32x64 round. R0 skeleton: block = 4 waves, 32 tokens; grid 1024 -> 4
// blocks/CU = 16 waves/CU; 2 barriers/domain. Same LDS/global traffic as
// R0/R7 (12 b128 reads + 12 b32 writes + 8 weight b128 per wave-domain),
// but HALF the MFMA instructions at the 25%-faster 32x32 rate:
//   GEMM1: mid[256][32] -> wave w owns tiles mt=2w,2w+1 (rows 64w..64w+64),
//          each tile = 2 chained K=64 MFMAs (K=128).
//   GEMM2: h[128][32] -> wave w owns e-tile w (e 32w..32w+32), K=256 =
//          4 MFMAs split into TWO 2-deep chains (partial p0 + hm master,
//          merged by one vector add) for antiphase-equivalent ILP.
// C-layout (HW-verified, shape-determined): col = lane&31 = token,
//   row = 8*(reg>>2) + 4*(lane>>5) + (reg&3)  -> 4 contiguous rows per
//   dword -> packs/stores stay 4x b32 / 4x 16B as before.
// h master fp32 x131072 in regs (floatx16, e = 32w+8q+4hi+r, tok = lane&31);
// GEMM2 accumulates into it. h fp8 = x8 (hm*2^-14); mid fp8 =
// mask*512*0.1*gelu = acc*(k0+k1*acc), k0=0.0125, k1=4.87035e-6 (acc=2048x).
// LDS: mid [0,8K) rows tok*256; h [8K,12K) rows tok*128; fp32 stag at init.
// XOR-16B-unit swizzle keyed by tok&7 (same key writer+reader, bijective
// within 8-unit groups; unit bit3 preserved on mid).
// Weight tuples int8v with UNDEFINED tops (cbsz=4: fp4 A reads regs[0:3]
// only -- HW-proven); B (fp8) uses all 8 dwords. W2[d] loaded at loop top
// (flies over phase A); W1[d+1] prefetched at end of phase A (R4 pattern).
// ---------------------------------------------------------------------------
__launch_bounds__(256, 4)
__global__ void domain_chain(const int* __restrict__ x,
                             const float* __restrict__ base_embed,
                             const int* __restrict__ membership,
                             const unsigned char* __restrict__ W1f,
                             const unsigned char* __restrict__ W2f,
                             float* __restrict__ out) {
  __shared__ __align__(16) unsigned char act[16384];
  __shared__ int xs[32];
  __shared__ int mws[32];

  const int tid = threadIdx.x;       // 0..255
  const int w = tid >> 6;            // wave 0..3
  const int lane = tid & 63;
  const int tok = lane & 31;         // token owned by this lane (C col)
  const int hi = lane >> 5;
  const int key = tok & 7;
  const int tokbase = blockIdx.x * 32;

  if (tid < 32) xs[tid] = x[tokbase + tid];
  __syncthreads();
  if (tid >= 32 && tid < 64) {
    int t = tid - 32;
    int tk = xs[t];
    int mw = 0;
#pragma unroll
    for (int d = 0; d < 16; ++d)
      mw |= (membership[d * VOCAB + tk] != 0 ? 1 : 0) << d;
    mws[t] = mw;
  }
  // stage h0 fp32 (32 tok x 128 f32 = 16 KB), float4 units swizzled ^(t&7)
  float4* stag4 = (float4*)act;
#pragma unroll
  for (int i = 0; i < 4; ++i) {
    int idx = tid + i * 256;         // 0..1023
    int t = idx >> 5, c4 = idx & 31;
    stag4[t * 32 + (c4 ^ (t & 7))] = ((const float4*)base_embed)[(size_t)xs[t] * 32 + c4];
  }
  __syncthreads();

  // h master fp32 x131072 (32x32 C-layout): hm[4q+r] =
  //   131072 * h[e = 32w + 8q + 4hi + r][tok]
  floatx16 hm;
  const int mwr = mws[tok];
#pragma unroll
  for (int q = 0; q < 4; ++q) {
    float4 v = stag4[tok * 32 + ((8 * w + 2 * q + hi) ^ key)];
    hm[4 * q + 0] = v.x * 131072.f;
    hm[4 * q + 1] = v.y * 131072.f;
    hm[4 * q + 2] = v.z * 131072.f;
    hm[4 * q + 3] = v.w * 131072.f;
  }

  // domain-invariant LDS byte addrs (16B units XOR-swizzled by key)
  // mid rows tok*256 (16 units); h rows 8192 + tok*128 (8 units)
  const int mrow = tok * 256;
  const int hrow = 8192 + tok * 128;
  int mwa[2][4], hwa[4], mra[4][2], hra[2][2];
#pragma unroll
  for (int t = 0; t < 2; ++t)
#pragma unroll
    for (int q = 0; q < 4; ++q)
      mwa[t][q] = mrow + (((2 * (2 * w + t) + (q >> 1)) ^ key) << 4) + 8 * (q & 1) + 4 * hi;
#pragma unroll
  for (int q = 0; q < 4; ++q)
    hwa[q] = hrow + (((2 * w + (q >> 1)) ^ key) << 4) + 8 * (q & 1) + 4 * hi;
#pragma unroll
  for (int kq = 0; kq < 4; ++kq)
#pragma unroll
    for (int u = 0; u < 2; ++u)
      mra[kq][u] = mrow + (((4 * kq + 2 * hi + u) ^ key) << 4);
#pragma unroll
  for (int kh = 0; kh < 2; ++kh)
#pragma unroll
    for (int u = 0; u < 2; ++u)
      hra[kh][u] = hrow + (((4 * kh + 2 * hi + u) ^ key) << 4);

  __syncthreads();   // stag reads done; act reused as mid/h

  // publish initial h fp8 (x8 = hm * 2^-14)
#pragma unroll
  for (int q = 0; q < 4; ++q)
    *(int*)(act + hwa[q]) =
        pack_fp8(hm[4 * q + 0] * 6.1035156e-5f, hm[4 * q + 1] * 6.1035156e-5f,
                 hm[4 * q + 2] * 6.1035156e-5f, hm[4 * q + 3] * 6.1035156e-5f);
  __syncthreads();

  const floatx16 vz16 = {0.f, 0.f, 0.f, 0.f, 0.f, 0.f, 0.f, 0.f,
                         0.f, 0.f, 0.f, 0.f, 0.f, 0.f, 0.f, 0.f};
  const size_t laneoff = (size_t)lane * 16;

  // persistent weight tuples: loads write low intx4 halves, tops UNDEFINED
  int8v aw8[4];   // W1[d]: idx t*2+kh (tile t=0,1; K-half kh)
  int8v bw8[4];   // W2[d]: idx kq (e-tile = w)
  {
    const unsigned char* w1d = W1f + (size_t)(w * 4) * 1024 + laneoff;
#pragma unroll
    for (int j = 0; j < 4; ++j)
      *(intx4*)&aw8[j] = *(const intx4*)(w1d + j * 1024);
  }

#pragma unroll 1
  for (int d = 0; d < 16; ++d) {
    // loop top: this domain's W2 frags (in flight during phase A)
    {
      const unsigned char* w2d = W2f + ((size_t)d << 14) + (size_t)(w * 4) * 1024 + laneoff;
#pragma unroll
      for (int j = 0; j < 4; ++j)
        *(intx4*)&bw8[j] = *(const intx4*)(w2d + j * 1024);
    }

    // ---- phase A: GEMM1 (m=64 slice = 2 tiles, n=32, K=128 = 2 mfma/tile)
    int8v hb[2];
#pragma unroll
    for (int kh = 0; kh < 2; ++kh) {
      ((intx4*)&hb[kh])[0] = *(const intx4*)(act + hra[kh][0]);
      ((intx4*)&hb[kh])[1] = *(const intx4*)(act + hra[kh][1]);
    }
    const float on = ((mwr >> d) & 1) ? 1.f : 0.f;
    const float k0 = 0.0125f * on;
    const float k1 = 4.87035e-6f * on;
    // mid_stored = mask * acc*(k0 + k1*acc)   [= 512*0.1*gelu(acc/2048)]
#pragma unroll
    for (int t = 0; t < 2; ++t) {
      floatx16 a = MFMA32(aw8[t * 2 + 0], hb[0], vz16);
      a = MFMA32(aw8[t * 2 + 1], hb[1], a);
#pragma unroll
      for (int q = 0; q < 4; ++q) {
        floatx4 v = {a[4 * q + 0], a[4 * q + 1], a[4 * q + 2], a[4 * q + 3]};
        floatx4 tt = v * (k0 + k1 * v);
        *(int*)(act + mwa[t][q]) = pack_fp8(tt[0], tt[1], tt[2], tt[3]);
      }
    }
    // prefetch NEXT domain's W1 into aw8 (dead after the mfmas above);
    // in flight across barrier + phase B + barrier.
    {
      const unsigned char* w1n = W1f + ((size_t)(d + 1) << 14) + (size_t)(w * 4) * 1024 + laneoff;
#pragma unroll
      for (int j = 0; j < 4; ++j)
        *(intx4*)&aw8[j] = *(const intx4*)(w1n + j * 1024);
      // (d=15: overreads into W2f workspace: benign)
    }
    __syncthreads();   // mid visible; all phase-A h reads done

    // ---- phase B: GEMM2 (e-tile w, n=32, K=256 = 4 mfma, two 2-deep chains)
    int8v mb0, mb1;
    ((intx4*)&mb0)[0] = *(const intx4*)(act + mra[0][0]);
    ((intx4*)&mb0)[1] = *(const intx4*)(act + mra[0][1]);
    ((intx4*)&mb1)[0] = *(const intx4*)(act + mra[1][0]);
    ((intx4*)&mb1)[1] = *(const intx4*)(act + mra[1][1]);
    floatx16 p0 = MFMA32(bw8[0], mb0, vz16);
    p0 = MFMA32(bw8[1], mb1, p0);
    ((intx4*)&mb0)[0] = *(const intx4*)(act + mra[2][0]);
    ((intx4*)&mb0)[1] = *(const intx4*)(act + mra[2][1]);
    ((intx4*)&mb1)[0] = *(const intx4*)(act + mra[3][0]);
    ((intx4*)&mb1)[1] = *(const intx4*)(act + mra[3][1]);
    hm = MFMA32(bw8[2], mb0, hm);
    hm = MFMA32(bw8[3], mb1, hm);
    hm = hm + p0;
    // republish h fp8 (x8 = hm * 2^-14)
#pragma unroll
    for (int q = 0; q < 4; ++q)
      *(int*)(act + hwa[q]) =
          pack_fp8(hm[4 * q + 0] * 6.1035156e-5f, hm[4 * q + 1] * 6.1035156e-5f,
                   hm[4 * q + 2] * 6.1035156e-5f, hm[4 * q + 3] * 6.1035156e-5f);
    __syncthreads();
  }

  // ---- epilogue: out[token][e] fp32 = hm / 131072, 16B stores
  const float inv = 1.0f / 131072.0f;
#pragma unroll
  for (int q = 0; q < 4; ++q) {
    float4 v = {hm[4 * q + 0] * inv, hm[4 * q + 1] * inv,
                hm[4 * q + 2] * inv, hm[4 * q + 3] * inv};
    *(float4*)&out[(size_t)(tokbase + tok) * 128 + 32 * w + 8 * q + 4 * hi] = v;
  }
}

extern "C" void kernel_launch(void* const* d_in, const int* in_sizes, int n_in,
                              void* d_out, int out_size, void* d_ws, size_t ws_size,
                              hipStream_t stream) {
  const int* x = (const int*)d_in[0];
  const float* base_embed = (const float*)d_in[1];
  const float* W1 = (const float*)d_in[2];
  const float* W2 = (const float*)d_in[3];
  const int* membership = (const int*)d_in[4];
  float* out = (float*)d_out;

  unsigned* W1f = (unsigned*)d_ws;                 // 16 dom x 16KB = 256KB fp4
  unsigned* W2f = W1f + 16 * 4096;                 // 256KB (d=15 W1 prefetch
                                                   // overreads into this: benign)

  prep_weights<<<512, 256, 0, stream>>>(W1, W2, W1f, W2f);

  const int n_tokens = in_sizes[0];                // 32768
  domain_chain<<<n_tokens / 32, 256, 0, stream>>>(
      x, base_embed, membership, (const unsigned char*)W1f, (const unsigned char*)W2f, out);
}

// Round 10
// 126.027 us; speedup vs baseline: 1.0482x; 1.0482x over previous
//
#include <hip/hip_runtime.h>

#define VOCAB 50257

typedef __attribute__((ext_vector_type(4))) float floatx4;
typedef __attribute__((ext_vector_type(4))) int intx4;
typedef __attribute__((ext_vector_type(8))) int int8v;

// identity E8M0 scales (2^0) in every byte -> opsel-proof
#define SC1 0x7F7F7F7F
#define MFMA_F4F8(a, b, c) \
  __builtin_amdgcn_mfma_scale_f32_16x16x128_f8f6f4((a), (b), (c), 4, 0, 0, SC1, 0, SC1)

// ---------------------------------------------------------------------------
// fp4 e2m1 quantizer (software RNE-ish to grid {0,.5,1,1.5,2,3,4,6}), x256.
// ---------------------------------------------------------------------------
static __device__ __forceinline__ unsigned fp4q(float v) {
  float a = fabsf(v) * 256.f;
  unsigned s = (v < 0.f) ? 8u : 0u;
  unsigned c;
  if (a < 0.25f) c = 0;
  else if (a < 0.75f) c = 1;
  else if (a < 1.25f) c = 2;
  else if (a < 1.75f) c = 3;
  else if (a < 2.5f)  c = 4;
  else if (a < 3.5f)  c = 5;
  else if (a < 5.0f)  c = 6;
  else c = 7;
  return s | c;
}

// ---------------------------------------------------------------------------
// Weight pre-shuffle: fp32 -> fp4 (x256), frag-major for K=128 scaled MFMA.
// A-frag: A[m = lane&15][k = 32*(lane>>4) + 8*r + j], r=dword 0..3, j=nibble.
// W1f dword idx (per domain, 4096 dw): ((p*64+lane)*4 + r), p = 4w+mt:
//   -> W1[d][16p + (l&15)][32*(l>>4) + 8r + j]
// W2f: p = (2w+et)*2 + kh -> W2[d][16*(p>>1) + (l&15)][128*(p&1) + 32*(l>>4) + 8r + j]
// ---------------------------------------------------------------------------
__global__ void prep_weights(const float* __restrict__ W1, const float* __restrict__ W2,
                             unsigned* __restrict__ W1f, unsigned* __restrict__ W2f) {
  int g = blockIdx.x * 256 + threadIdx.x;   // 0..131071
  int arr = g >> 16;
  int s = g & 65535;
  int d = s >> 12;
  int gg = s & 4095;         // dword within domain
  int p = gg >> 8;           // 0..15
  int lane = (gg >> 2) & 63;
  int r = gg & 3;
  int lm = lane & 15, lq = lane >> 4;
  const float* src;
  unsigned* dst;
  if (arr == 0) {
    src = W1 + (size_t)(d * 256 + 16 * p + lm) * 128 + 32 * lq + 8 * r;
    dst = W1f + (size_t)d * 4096 + gg;
  } else {
    src = W2 + (size_t)(d * 128 + 16 * (p >> 1) + lm) * 256 + 128 * (p & 1) + 32 * lq + 8 * r;
    dst = W2f + (size_t)d * 4096 + gg;
  }
  unsigned pk = 0;
#pragma unroll
  for (int j = 0; j < 8; ++j) pk |= fp4q(src[j]) << (4 * j);
  *dst = pk;
}

static __device__ __forceinline__ int pack_fp8(float a, float b, float c, float d) {
  int v = __builtin_amdgcn_cvt_pk_fp8_f32(a, b, 0, false);
  return __builtin_amdgcn_cvt_pk_fp8_f32(c, d, v, true);
}

// ---------------------------------------------------------------------------
// R7 two-stream antiphase base (proven 48.7us) + T5 s_setprio around MFMA
// clusters (4 drifting blocks/CU + role-diverse intervals = the regime where
// setprio pays) + h-read issued before mid-read (GEMM1's chain is longer).
// Block = 4 waves, 32 tokens; grid 1024 -> 4 blocks/CU = 16 waves/CU.
// Streams s0/s1 (16 tok) in antiphase: every barrier interval carries two
// independent chains (GEMM2(sA,d) || GEMM1(sB,d')).
// GEMM1 m-split (wave w -> mid rows 64w..64w+64 of its stream); GEMM2
// e-split (wave w -> e 32w..32w+32). K=128 scaled MFMA, A = fp4 (x256,
// identity scales), B = fp8 act. h master fp32 x131072 in regs hm[et][s].
// h fp8 = x8 (hm*2^-14); mid fp8 = mask*512*0.1*gelu = acc*(k0+k1*acc),
// k0=0.0125, k1=4.87035e-6 (acc=2048x).
// LDS per stream s: mid at s*6144 (16 rows x 256B), h at s*6144+4096
// (16 rows x 128B); fp32 stag [0,16K) at init. XOR-16B-unit swizzle keyed
// by row&7 (reader AND writer; write banks 4u+lq = 2-way free -- R8's
// 4-way write-conflict lesson).
// Weights single-buffered: W1[d] serves X_d,Y_d (prefetch W1[d+1] end of
// Y_d); W2[d] serves Y_d,X_{d+1} (prefetch W2[d+1] end of X_{d+1}).
// int8v weight tuples with UNDEFINED tops (cbsz=4: fp4 A reads regs[0:3]
// only -- HW-proven); vector pack math (R4 VALU cuts).
// ---------------------------------------------------------------------------
__launch_bounds__(256, 4)
__global__ void domain_chain(const int* __restrict__ x,
                             const float* __restrict__ base_embed,
                             const int* __restrict__ membership,
                             const unsigned char* __restrict__ W1f,
                             const unsigned char* __restrict__ W2f,
                             float* __restrict__ out) {
  __shared__ __align__(16) unsigned char act[16384];
  __shared__ int xs[32];
  __shared__ int mws[32];

  const int tid = threadIdx.x;       // 0..255
  const int w = tid >> 6;            // wave 0..3
  const int lane = tid & 63;
  const int lm = lane & 15, lq = lane >> 4;
  const int key = lm & 7;
  const int tokbase = blockIdx.x * 32;

  if (tid < 32) xs[tid] = x[tokbase + tid];
  __syncthreads();
  if (tid >= 32 && tid < 64) {
    int t = tid - 32;
    int tok = xs[t];
    int mw = 0;
#pragma unroll
    for (int d = 0; d < 16; ++d)
      mw |= (membership[d * VOCAB + tok] != 0 ? 1 : 0) << d;
    mws[t] = mw;
  }
  // stage h0 fp32 (32 tok x 128 f32 = 16 KB), float4 units swizzled ^(t&7)
  float4* stag4 = (float4*)act;
#pragma unroll
  for (int i = 0; i < 4; ++i) {
    int idx = tid + i * 256;         // 0..1023
    int t = idx >> 5, c4 = idx & 31;
    stag4[t * 32 + (c4 ^ (t & 7))] = ((const float4*)base_embed)[(size_t)xs[t] * 32 + c4];
  }
  __syncthreads();

  // h master fp32 x131072 (e-slice, MFMA C-layout): hm[et][s] reg r =
  //   131072 * h[e = 32w+16et+4lq+r][tok = 16s+lm]
  floatx4 hm[2][2];
  int mwr[2];
#pragma unroll
  for (int s = 0; s < 2; ++s) mwr[s] = mws[s * 16 + lm];
#pragma unroll
  for (int et = 0; et < 2; ++et)
#pragma unroll
    for (int s = 0; s < 2; ++s) {
      float4 v = stag4[(s * 16 + lm) * 32 + ((8 * w + 4 * et + lq) ^ key)];
      hm[et][s] = (floatx4){v.x * 131072.f, v.y * 131072.f, v.z * 131072.f, v.w * 131072.f};
    }

  // domain-invariant LDS byte offsets (16B units XOR-swizzled by key)
  const int mrow[2] = {lm * 256, 6144 + lm * 256};
  const int hrow[2] = {4096 + lm * 128, 6144 + 4096 + lm * 128};
  int sw[2], mwu[4], hwu[2];
#pragma unroll
  for (int u = 0; u < 2; ++u) sw[u] = ((2 * lq + u) ^ key) << 4;
#pragma unroll
  for (int mt = 0; mt < 4; ++mt) mwu[mt] = (((4 * w + mt) ^ key) << 4) + 4 * lq;
#pragma unroll
  for (int et = 0; et < 2; ++et) hwu[et] = (((2 * w + et) ^ key) << 4) + 4 * lq;

  __syncthreads();   // stag reads done; act reused as mid/h

  // publish initial h fp8 (x8 = hm * 2^-14), both streams
#pragma unroll
  for (int et = 0; et < 2; ++et)
#pragma unroll
    for (int s = 0; s < 2; ++s) {
      floatx4 v8 = hm[et][s] * 6.1035156e-5f;
      *(int*)(act + hrow[s] + hwu[et]) = pack_fp8(v8[0], v8[1], v8[2], v8[3]);
    }
  __syncthreads();

  const floatx4 vz = {0.f, 0.f, 0.f, 0.f};
  const size_t laneoff = (size_t)lane * 16;

  // persistent weight tuples, loads write low intx4 halves, tops UNDEFINED
  int8v aw8[4];    // W1[d] tiles 4w+mt
  int8v bw8[4];    // W2[d] tiles (2w+et)*2+kh
  {
    const unsigned char* w1d = W1f + (size_t)(w * 4) * 1024 + laneoff;
#pragma unroll
    for (int mt = 0; mt < 4; ++mt)
      *(intx4*)&aw8[mt] = *(const intx4*)(w1d + mt * 1024);
    const unsigned char* w2d = W2f + (size_t)(w * 4) * 1024 + laneoff;
#pragma unroll
    for (int j = 0; j < 4; ++j)
      *(intx4*)&bw8[j] = *(const intx4*)(w2d + j * 1024);
  }

  // ---- X_0: GEMM1(s0, d=0)
  {
    int8v hb;
    ((intx4*)&hb)[0] = *(const intx4*)(act + hrow[0] + sw[0]);
    ((intx4*)&hb)[1] = *(const intx4*)(act + hrow[0] + sw[1]);
    const float on = (mwr[0] & 1) ? 1.f : 0.f;
    const float k0 = 0.0125f * on, k1 = 4.87035e-6f * on;
    __builtin_amdgcn_s_setprio(1);
#pragma unroll
    for (int mt = 0; mt < 4; ++mt) {
      floatx4 a = MFMA_F4F8(aw8[mt], hb, vz);
      floatx4 t = a * (k0 + k1 * a);
      *(int*)(act + mrow[0] + mwu[mt]) = pack_fp8(t[0], t[1], t[2], t[3]);
    }
    __builtin_amdgcn_s_setprio(0);
  }
  __syncthreads();

#pragma unroll 1
  for (int d = 0; d < 15; ++d) {
    // ---- Y_d: GEMM2(s0,d) || GEMM1(s1,d); republish h_s0; prefetch W1[d+1]
    {
      // h-read first: GEMM1's chain (MFMA->gelu->pack->write) is the longer one
      int8v hb1, mb0[2];
      ((intx4*)&hb1)[0] = *(const intx4*)(act + hrow[1] + sw[0]);
      ((intx4*)&hb1)[1] = *(const intx4*)(act + hrow[1] + sw[1]);
#pragma unroll
      for (int kh = 0; kh < 2; ++kh) {
        ((intx4*)&mb0[kh])[0] = *(const intx4*)(act + mrow[0] + (8 * kh << 4) + sw[0]);
        ((intx4*)&mb0[kh])[1] = *(const intx4*)(act + mrow[0] + (8 * kh << 4) + sw[1]);
      }
      const float on = ((mwr[1] >> d) & 1) ? 1.f : 0.f;
      const float k0 = 0.0125f * on, k1 = 4.87035e-6f * on;
      __builtin_amdgcn_s_setprio(1);
      // GEMM1 s1 (chain B)
#pragma unroll
      for (int mt = 0; mt < 4; ++mt) {
        floatx4 a = MFMA_F4F8(aw8[mt], hb1, vz);
        floatx4 t = a * (k0 + k1 * a);
        *(int*)(act + mrow[1] + mwu[mt]) = pack_fp8(t[0], t[1], t[2], t[3]);
      }
      // GEMM2 s0 (chain A, independent)
#pragma unroll
      for (int et = 0; et < 2; ++et)
#pragma unroll
        for (int kh = 0; kh < 2; ++kh)
          hm[et][0] = MFMA_F4F8(bw8[et * 2 + kh], mb0[kh], hm[et][0]);
      __builtin_amdgcn_s_setprio(0);
      // republish h_s0
#pragma unroll
      for (int et = 0; et < 2; ++et) {
        floatx4 v8 = hm[et][0] * 6.1035156e-5f;
        *(int*)(act + hrow[0] + hwu[et]) = pack_fp8(v8[0], v8[1], v8[2], v8[3]);
      }
      // prefetch W1[d+1] (aw8 dead after s1's MFMAs above)
      const unsigned char* w1n = W1f + ((size_t)(d + 1) << 14) + (size_t)(w * 4) * 1024 + laneoff;
#pragma unroll
      for (int mt = 0; mt < 4; ++mt)
        *(intx4*)&aw8[mt] = *(const intx4*)(w1n + mt * 1024);
    }
    __syncthreads();

    // ---- X_{d+1}: GEMM1(s0,d+1) || GEMM2(s1,d); republish h_s1; prefetch W2[d+1]
    {
      int8v hb0, mb1[2];
      ((intx4*)&hb0)[0] = *(const intx4*)(act + hrow[0] + sw[0]);
      ((intx4*)&hb0)[1] = *(const intx4*)(act + hrow[0] + sw[1]);
#pragma unroll
      for (int kh = 0; kh < 2; ++kh) {
        ((intx4*)&mb1[kh])[0] = *(const intx4*)(act + mrow[1] + (8 * kh << 4) + sw[0]);
        ((intx4*)&mb1[kh])[1] = *(const intx4*)(act + mrow[1] + (8 * kh << 4) + sw[1]);
      }
      const float on = ((mwr[0] >> (d + 1)) & 1) ? 1.f : 0.f;
      const float k0 = 0.0125f * on, k1 = 4.87035e-6f * on;
      __builtin_amdgcn_s_setprio(1);
      // GEMM1 s0 (domain d+1)
#pragma unroll
      for (int mt = 0; mt < 4; ++mt) {
        floatx4 a = MFMA_F4F8(aw8[mt], hb0, vz);
        floatx4 t = a * (k0 + k1 * a);
        *(int*)(act + mrow[0] + mwu[mt]) = pack_fp8(t[0], t[1], t[2], t[3]);
      }
      // GEMM2 s1 (domain d, independent)
#pragma unroll
      for (int et = 0; et < 2; ++et)
#pragma unroll
        for (int kh = 0; kh < 2; ++kh)
          hm[et][1] = MFMA_F4F8(bw8[et * 2 + kh], mb1[kh], hm[et][1]);
      __builtin_amdgcn_s_setprio(0);
      // republish h_s1
#pragma unroll
      for (int et = 0; et < 2; ++et) {
        floatx4 v8 = hm[et][1] * 6.1035156e-5f;
        *(int*)(act + hrow[1] + hwu[et]) = pack_fp8(v8[0], v8[1], v8[2], v8[3]);
      }
      // prefetch W2[d+1] (bw8 dead after s1's MFMAs above)
      const unsigned char* w2n = W2f + ((size_t)(d + 1) << 14) + (size_t)(w * 4) * 1024 + laneoff;
#pragma unroll
      for (int j = 0; j < 4; ++j)
        *(intx4*)&bw8[j] = *(const intx4*)(w2n + j * 1024);
    }
    __syncthreads();
  }

  // ---- Y_15: GEMM2(s0,15) || GEMM1(s1,15); no republish/prefetch for s0
  {
    int8v hb1, mb0[2];
    ((intx4*)&hb1)[0] = *(const intx4*)(act + hrow[1] + sw[0]);
    ((intx4*)&hb1)[1] = *(const intx4*)(act + hrow[1] + sw[1]);
#pragma unroll
    for (int kh = 0; kh < 2; ++kh) {
      ((intx4*)&mb0[kh])[0] = *(const intx4*)(act + mrow[0] + (8 * kh << 4) + sw[0]);
      ((intx4*)&mb0[kh])[1] = *(const intx4*)(act + mrow[0] + (8 * kh << 4) + sw[1]);
    }
    const float on = ((mwr[1] >> 15) & 1) ? 1.f : 0.f;
    const float k0 = 0.0125f * on, k1 = 4.87035e-6f * on;
    __builtin_amdgcn_s_setprio(1);
#pragma unroll
    for (int mt = 0; mt < 4; ++mt) {
      floatx4 a = MFMA_F4F8(aw8[mt], hb1, vz);
      floatx4 t = a * (k0 + k1 * a);
      *(int*)(act + mrow[1] + mwu[mt]) = pack_fp8(t[0], t[1], t[2], t[3]);
    }
#pragma unroll
    for (int et = 0; et < 2; ++et)
#pragma unroll
      for (int kh = 0; kh < 2; ++kh)
        hm[et][0] = MFMA_F4F8(bw8[et * 2 + kh], mb0[kh], hm[et][0]);
    __builtin_amdgcn_s_setprio(0);
  }
  __syncthreads();

  // ---- X_16: GEMM2(s1,15) only
  {
    int8v mb1[2];
#pragma unroll
    for (int kh = 0; kh < 2; ++kh) {
      ((intx4*)&mb1[kh])[0] = *(const intx4*)(act + mrow[1] + (8 * kh << 4) + sw[0]);
      ((intx4*)&mb1[kh])[1] = *(const intx4*)(act + mrow[1] + (8 * kh << 4) + sw[1]);
    }
    __builtin_amdgcn_s_setprio(1);
#pragma unroll
    for (int et = 0; et < 2; ++et)
#pragma unroll
      for (int kh = 0; kh < 2; ++kh)
        hm[et][1] = MFMA_F4F8(bw8[et * 2 + kh], mb1[kh], hm[et][1]);
    __builtin_amdgcn_s_setprio(0);
  }

  // ---- epilogue: out[token][e] fp32 = hm / 131072, 16B stores
  const float inv = 1.0f / 131072.0f;
#pragma unroll
  for (int et = 0; et < 2; ++et)
#pragma unroll
    for (int s = 0; s < 2; ++s) {
      floatx4 v = hm[et][s] * inv;
      *(floatx4*)&out[(size_t)(tokbase + s * 16 + lm) * 128 + 32 * w + 16 * et + 4 * lq] = v;
    }
}

extern "C" void kernel_launch(void* const* d_in, const int* in_sizes, int n_in,
                              void* d_out, int out_size, void* d_ws, size_t ws_size,
                              hipStream_t stream) {
  const int* x = (const int*)d_in[0];
  const float* base_embed = (const float*)d_in[1];
  const float* W1 = (const float*)d_in[2];
  const float* W2 = (const float*)d_in[3];
  const int* membership = (const int*)d_in[4];
  float* out = (float*)d_out;

  unsigned* W1f = (unsigned*)d_ws;                 // 16 dom x 16KB = 256KB fp4
  unsigned* W2f = W1f + 16 * 4096;                 // 256KB

  prep_weights<<<512, 256, 0, stream>>>(W1, W2, W1f, W2f);

  const int n_tokens = in_sizes[0];                // 32768
  domain_chain<<<n_tokens / 32, 256, 0, stream>>>(
      x, base_embed, membership, (const unsigned char*)W1f, (const unsigned char*)W2f, out);
}